// Round 13
// baseline (314.740 us; speedup 1.0000x reference)
//
#include <hip/hip_runtime.h>
#include <math.h>

constexpr float DXC    = 3.125f;                              // 400/128
constexpr float INV_DX = 0.32f;                               // 1/3.125
constexpr float XMINC  = -200.0f;
constexpr float KW2    = 9.0f * 3.14159265358979323846f;      // cutoff^2 (mm^2)
constexpr float DXC2   = DXC * DXC;                           // 9.765625
constexpr float NEGL2C = -(2.0f / KW2) * 1.4426950408889634f * DXC2; // exp2 scale (cell^2)
constexpr float WOFF   = 1.7983f;                             // window anchor offset
constexpr float WMIN   = 0.13533528323661270f;                // e^-2: product-space gate

constexpr int TPB    = 1024;   // threads per block = LORs per block
constexpr int LPB    = 1024;
constexpr int KSPLIT = 8;
constexpr int KCH    = 128 / KSPLIT;
constexpr int QTAB   = 1024;   // weight-table bins over s in [0,4)

typedef __fp16 half2_t __attribute__((ext_vector_type(2)));

__device__ inline ushort f16_rn(float x) {
    union { __fp16 h; ushort u; } cv;
    cv.h = (__fp16)x;                   // v_cvt_f16_f32 (RNE)
    return cv.u;
}
__device__ inline uint pk_f16(float x, float y) {
    union { half2_t h; uint u; } cv;
    cv.h = __builtin_amdgcn_cvt_pkrtz(x, y);
    return cv.u;
}

// ---- prep: f16 volumes, slice-contiguous [k][i][j] layouts per axis
__global__ __launch_bounds__(256) void prep_kernel(const float* __restrict__ img,
                                                   ushort* __restrict__ V0,
                                                   ushort* __restrict__ V1,
                                                   ushort* __restrict__ V2) {
    int o = blockIdx.x * 256 + threadIdx.x;
    float x = img[o];
    ushort h = f16_rn(x);
    V0[o] = h;
    int c = o & 127, b = (o >> 7) & 127, a = o >> 14;
    V1[(b << 14) | (a << 7) | c] = h;
    int j = o & 127, i = (o >> 7) & 127, k = o >> 14;
    V2[o] = f16_rn(img[(i << 14) | (j << 7) | k]);
}

__global__ __launch_bounds__(1024) void zero_kernel(float* __restrict__ out, int m) {
    int i = blockIdx.x * 1024 + threadIdx.x;
    if (i < m) out[i] = 0.0f;
}

// ---- staging: 32KB f16 slice global->LDS DMA (R11-exact)
__device__ inline void stage_one(const ushort* __restrict__ V, int k, int tid, void* dst) {
    const char* src = (const char*)(V + ((size_t)k << 14));
    char* d = (char*)dst;
    int wbase = (tid >> 6) << 10;           // wave * 1024 bytes
    int lane16 = (tid & 63) << 4;
#pragma unroll
    for (int c = 0; c < 2; ++c) {
        int half = c << 14;                 // 0 / 16384
        __builtin_amdgcn_global_load_lds(
            (__attribute__((address_space(1))) void*)(const_cast<char*>(src + half + wbase + lane16)),
            (__attribute__((address_space(3))) void*)(d + half + wbase),
            16, 0, 0);
    }
}

// Fallback staging (no ws): fp32 global -> regs -> convert f16 -> LDS
template <int AXIS>
__device__ inline void stage_issue(const float* __restrict__ img, int k, int tid,
                                   float4 st[4]) {
#pragma unroll
    for (int c = 0; c < 4; ++c) {
        int f4 = tid + TPB * c;
        int fl = f4 << 2;
        if (AXIS == 2) {
            int i = fl >> 7, j = fl & 127;
            const float* p = img + (i << 14) + (j << 7) + k;
            st[c] = make_float4(p[0], p[128], p[256], p[384]);
        } else {
            int off;
            if (AXIS == 1) off = ((fl >> 7) << 14) | (k << 7) | (fl & 127);
            else           off = (k << 14) | fl;
            st[c] = *reinterpret_cast<const float4*>(img + off);
        }
    }
}

__device__ inline void stage_write(const float4 st[4], ushort* slb, int tid) {
    uint* w = reinterpret_cast<uint*>(slb);
#pragma unroll
    for (int c = 0; c < 4; ++c) {
        int f4 = tid + TPB * c;
        w[f4 * 2]     = pk_f16(st[c].x, st[c].y);
        w[f4 * 2 + 1] = pk_f16(st[c].z, st[c].w);
    }
}

// ---- window state (product-gate: no quadratic chains, no thr) ----
struct WIN { float4 ea, eb; int rowdw, sh; };

__device__ inline WIN mkwin(float u, float v, const float4* wt) {
    WIN w;
    float e0f = __builtin_amdgcn_fmed3f(floorf(v - WOFF), 0.0f, 124.0f);
    float i0f = __builtin_amdgcn_fmed3f(floorf(u - WOFF), 0.0f, 124.0f);
    int qv = (int)((v - e0f) * (QTAB / 4.0f));   // s in [0,4) -> no clamp needed
    int qu = (int)((u - i0f) * (QTAB / 4.0f));
    w.eb = wt[qv];
    w.ea = wt[qu];
    int e0 = (int)e0f, i0 = (int)i0f;
    w.sh    = (e0 & 1) << 4;
    w.rowdw = (i0 << 6) + (e0 >> 1);
    return w;
}

// 4x4 taps: 3 dwords/row, alignbit funnel, product gate, f16 unpack + fma
__device__ inline float do_slice(const WIN& w, const uint* __restrict__ s32, float acc) {
    float eaa[4] = {w.ea.x, w.ea.y, w.ea.z, w.ea.w};
#pragma unroll
    for (int r = 0; r < 4; ++r) {
        const uint* sr = s32 + w.rowdw + (r << 6);
        uint d0 = sr[0], d1 = sr[1], d2 = sr[2];
        uint p01 = __builtin_amdgcn_alignbit(d1, d0, w.sh);
        uint p23 = __builtin_amdgcn_alignbit(d2, d1, w.sh);
        float er = eaa[r];
        float g0 = er * w.eb.x, g1 = er * w.eb.y, g2 = er * w.eb.z, g3 = er * w.eb.w;
        g0 = (g0 >= WMIN) ? g0 : 0.0f;
        g1 = (g1 >= WMIN) ? g1 : 0.0f;
        g2 = (g2 >= WMIN) ? g2 : 0.0f;
        g3 = (g3 >= WMIN) ? g3 : 0.0f;
        union { uint u; half2_t h; } a01, a23;
        a01.u = p01; a23.u = p23;
        float x0 = (float)a01.h.x, x1 = (float)a01.h.y;
        float x2 = (float)a23.h.x, x3 = (float)a23.h.y;
        float rs = __fmul_rn(g0, x0);
        rs = fmaf(g1, x1, rs);
        rs = fmaf(g2, x2, rs);
        rs = fmaf(g3, x3, rs);
        acc += rs;
    }
    return acc;
}

template <int AXIS, bool PRE>
__device__ void proj_axis(ushort (*sl)[16384], float4* wtab,
                          const ushort* __restrict__ V,
                          const float*  __restrict__ imgF,
                          const float*  __restrict__ lors,
                          float* __restrict__ out, int n, int blk, int ks)
{
    const int tid = threadIdx.x;
    const int lor = blk * LPB + tid;
    const bool active = lor < n;
    const int lorc = active ? lor : n - 1;

    const float* l = lors + (size_t)lorc * 6;
    float l0 = l[0], l1 = l[1], l2 = l[2], l3 = l[3], l4 = l[4], l5 = l[5];
    float p0x, p0y, p0z, p1x, p1y, p1z;
    if (AXIS == 0)      { p0x = l1; p0y = l2; p0z = l0; p1x = l4; p1y = l5; p1z = l3; }
    else if (AXIS == 1) { p0x = l0; p0y = l2; p0z = l1; p1x = l3; p1y = l5; p1z = l4; }
    else                { p0x = l0; p0y = l1; p0z = l2; p1x = l3; p1y = l4; p1z = l5; }

    float dvx = p1x - p0x, dvy = p1y - p0y, dvz = p1z - p0z;
    float L     = sqrtf(dvx * dvx + dvy * dvy + dvz * dvz);
    float pathL = DXC * L / fabsf(dvz);
    float invdz = 1.0f / dvz;

    float dux  = dvx * INV_DX, ux0 = (p0x - XMINC) * INV_DX;
    float dvyS = dvy * INV_DX, vy0 = (p0y - XMINC) * INV_DX;
    float tzs = invdz, tz0 = -p0z * invdz;
    // t in [0,1] vacuous: per-axis LOR endpoints sit on the +-half faces.

    const int k0 = ks * KCH, k1 = k0 + KCH;

    float dt = DXC * tzs;
    float cu = dux * dt, cv = dvyS * dt;
    float zc0 = fmaf((float)k0, DXC, XMINC + 0.5f * DXC);
    float t0  = fmaf(zc0, tzs, tz0);
    float u   = fmaf(t0, dux, ux0);
    float v   = fmaf(t0, dvyS, vy0);
    float acc = 0.0f;

    // prologue: issue slice-k0 staging, fill weight table under it
    if (PRE) {
        stage_one(V, k0, tid, sl[k0 & 1]);
    } else {
        float4 st[4];
        stage_issue<AXIS>(imgF, k0, tid, st);
        stage_write(st, sl[k0 & 1], tid);
    }
    {   // wtab[q] = 4-row weights at sub-window offset s=(q+0.5)*4/QTAB
        float s = ((float)tid + 0.5f) * (4.0f / (float)QTAB);
        float4 e;
        float o0 = 0.5f - s, o1 = 1.5f - s, o2 = 2.5f - s, o3 = 3.5f - s;
        e.x = exp2f(o0 * o0 * NEGL2C);
        e.y = exp2f(o1 * o1 * NEGL2C);
        e.z = exp2f(o2 * o2 * NEGL2C);
        e.w = exp2f(o3 * o3 * NEGL2C);
        wtab[tid] = e;
    }
    __syncthreads();

    WIN w = mkwin(u, v, wtab);

    for (int k = k0; k < k1; ++k) {
        const ushort* sbuf = sl[k & 1];
        float4 st2[4];
        if (k < k1 - 1) {                       // issue next-slice loads early (dbuf)
            if (PRE) stage_one(V, k + 1, tid, sl[(k & 1) ^ 1]);
            else     stage_issue<AXIS>(imgF, k + 1, tid, st2);
        }

        acc = do_slice(w, reinterpret_cast<const uint*>(sbuf), acc);

        u += cu; v += cv;
        if (k < k1 - 1) {
            w = mkwin(u, v, wtab);              // VALU+table only: overlaps DMA
            if (!PRE) stage_write(st2, sl[(k & 1) ^ 1], tid);
            __syncthreads();                    // drains DMA -> slice k+1 ready
        }
    }

    if (active) atomicAdd(out + lor, acc * pathL);
}

template <bool PRE>
__global__ __launch_bounds__(TPB, 8) void proj_fused(const float* __restrict__ img,
                                                     const ushort* __restrict__ V0,
                                                     const ushort* __restrict__ V1,
                                                     const ushort* __restrict__ V2,
                                                     const float* __restrict__ xl,
                                                     const float* __restrict__ yl,
                                                     const float* __restrict__ zl,
                                                     float* __restrict__ out,
                                                     int n, int nblk)
{
    __shared__ ushort sl[2][16384];   // 64 KiB double-buffered f16 slice
    __shared__ float4 wtab[QTAB];     // 16 KiB weight table
    int per = nblk * KSPLIT;
    int axis = blockIdx.x / per;
    int r = blockIdx.x - axis * per;
    int blk = r >> 3;                 // KSPLIT = 8
    int ks  = r & 7;
    if (axis == 0)      proj_axis<0, PRE>(sl, wtab, V0, img, xl, out, n, blk, ks);
    else if (axis == 1) proj_axis<1, PRE>(sl, wtab, V1, img, yl, out + n, n, blk, ks);
    else                proj_axis<2, PRE>(sl, wtab, V2, img, zl, out + 2 * (size_t)n, n, blk, ks);
}

extern "C" void kernel_launch(void* const* d_in, const int* in_sizes, int n_in,
                              void* d_out, int out_size, void* d_ws, size_t ws_size,
                              hipStream_t stream) {
    const float* img   = (const float*)d_in[0];
    const float* xlors = (const float*)d_in[1];
    const float* ylors = (const float*)d_in[2];
    const float* zlors = (const float*)d_in[3];
    float* out = (float*)d_out;

    int n = in_sizes[1] / 6;
    int nblk = (n + LPB - 1) / LPB;
    int m = 3 * n;

    zero_kernel<<<(m + 1023) / 1024, 1024, 0, stream>>>(out, m);

    constexpr size_t VOL = 128 * 128 * 128;
    bool pre = ws_size >= 3 * VOL * sizeof(ushort);
    int grid = 3 * nblk * KSPLIT;

    if (pre) {
        ushort* V0 = (ushort*)d_ws;
        ushort* V1 = V0 + VOL;
        ushort* V2 = V1 + VOL;
        prep_kernel<<<VOL / 256, 256, 0, stream>>>(img, V0, V1, V2);
        proj_fused<true><<<grid, TPB, 0, stream>>>(img, V0, V1, V2,
                                                   xlors, ylors, zlors, out, n, nblk);
    } else {
        proj_fused<false><<<grid, TPB, 0, stream>>>(img, nullptr, nullptr, nullptr,
                                                    xlors, ylors, zlors, out, n, nblk);
    }
}